// Round 4
// baseline (496.443 us; speedup 1.0000x reference)
//
#include <hip/hip_runtime.h>

// Correlation layer v8.
// v4 (308us): LDS + 2 barriers/chunk, synchronous staging -> latency-bound.
// v5 (FAILED): exec-masked global_load_lds -> wave-uniform LDS base shifted
//   edge tiles. Never mask global_load_lds.
// v6 (1037us): reg-staged pipeline but launch_bounds(576,5) -> 48 VGPR,
//   acc spilled (WRITE 2.5GB). v7 (256us): same at (576,2) -> 84 VGPR.
// v7 counters: Occupancy 25% = ONE 9-wave block resident (84 VGPR -> 128
//   bucket -> 16 wave slots/CU, 2 blocks need 18). Every per-chunk barrier +
//   vmcnt drain has no other block to hide behind: ~6400 cyc/chunk vs ~650
//   of issue. Plus 2.1e7 LDS bank-conflict cycles and ~105MB residual spill.
// v8: DELETE the synchronization problem. The LDS tile only existed to share
//   x2 rows across the 9 iz-waves; L1 does that for free (x2 working set
//   ~4.3KB/channel, 8:1 reuse). Each thread reads its 12-float x2 window
//   directly from global (3 float4/channel), no LDS, no barriers, no staging.
//   Waves fully independent -> latency hidden by ILP, not occupancy.
//   OOB: chunk-invariant predicates select a static zero-block pointer with
//   stride 0 (L1 broadcast) -> zero per-iteration masking cost.
//   XCD swizzle kept: bid&7 = one image per XCD -> inter-block L2 reuse.

#define B_  8
#define C_  128
#define H_  128
#define W_  192
#define HW_ (H_*W_)
#define WT  32              // tile width (px)
#define HT  8               // tile height (px)
#define NTHREADS 576        // 8 x 8 x 9 = 9 waves

__device__ static const __attribute__((aligned(16))) float g_zero[4] = {0.f, 0.f, 0.f, 0.f};

__global__ __launch_bounds__(NTHREADS, 2) void corr_kernel(
    const float* __restrict__ x1, const float* __restrict__ x2,
    float* __restrict__ out)
{
    const int tx = threadIdx.x;           // 0..7 : 4-px column group
    const int ty = threadIdx.y;           // 0..7 : row within tile
    const int iz = threadIdx.z;           // 0..8 : displacement row (one wave)

    // XCD swizzle: consecutive blockIdx round-robin over 8 XCDs; bid&7 pins
    // one batch image per XCD, tiles row-major within the image.
    const int bid = blockIdx.x;
    const int b   = bid & 7;
    const int t   = bid >> 3;             // 0..95
    const int w0t = (t % 6) * WT;
    const int h0t = (t / 6) * HT;

    const float* x1b = x1 + (size_t)b * C_ * HW_;
    const float* x2b = x2 + (size_t)b * C_ * HW_;

    const int h_out = h0t + ty;           // output row
    const int w_out = w0t + 4 * tx;       // output col (first of 4)

    // x1: this thread's 4 output pixels, one float4 per channel
    const float* x1p = x1b + (size_t)h_out * W_ + w_out;

    // x2 window: row r2 = h_out + (iz-4), cols w_out-4 .. w_out+11,
    // as 3 float4s at col bases c0,c1,c2 (each fully in- or out-of-bounds
    // since everything is 4-aligned and W_ % 4 == 0).
    const int r2 = h_out + iz - 4;
    const bool rowok = ((unsigned)r2 < (unsigned)H_);
    const int c0 = w_out - 4, c1 = w_out, c2 = w_out + 4;
    const bool ok0 = rowok && ((unsigned)c0 < (unsigned)W_);
    const bool ok1 = rowok;                               // c1 always in [0,188]
    const bool ok2 = rowok && ((unsigned)c2 < (unsigned)W_);

    const float* zp = g_zero;
    const float* p0 = ok0 ? (x2b + (size_t)r2 * W_ + c0) : zp;
    const float* p1 = ok1 ? (x2b + (size_t)r2 * W_ + c1) : zp;
    const float* p2 = ok2 ? (x2b + (size_t)r2 * W_ + c2) : zp;
    const int s0 = ok0 ? HW_ : 0;         // per-channel advance (floats)
    const int s1 = ok1 ? HW_ : 0;
    const int s2 = ok2 ? HW_ : 0;

    float acc[9][4];
    #pragma unroll
    for (int j = 0; j < 9; j++)
        #pragma unroll
        for (int p = 0; p < 4; p++) acc[j][p] = 0.f;

    #pragma unroll 2
    for (int c = 0; c < C_; ++c) {
        const float4 a  = *(const float4*)(x1p);
        const float4 w0 = *(const float4*)(p0);
        const float4 w1 = *(const float4*)(p1);
        const float4 w2 = *(const float4*)(p2);
        x1p += HW_; p0 += s0; p1 += s1; p2 += s2;

        const float av[4] = {a.x, a.y, a.z, a.w};
        const float rr[12] = {w0.x, w0.y, w0.z, w0.w,
                              w1.x, w1.y, w1.z, w1.w,
                              w2.x, w2.y, w2.z, w2.w};
        #pragma unroll
        for (int j = 0; j < 9; j++)
            #pragma unroll
            for (int p = 0; p < 4; p++)
                acc[j][p] = fmaf(av[p], rr[j + p], acc[j][p]);
    }

    // epilogue: scale + write up to 9 float4 channels
    const float scale = 0.08838834764831845f;   // 1/sqrt(128)
    float* outb = out + (size_t)b * 80 * HW_ + (size_t)h_out * W_ + w_out;
    #pragma unroll
    for (int j = 0; j < 9; j++) {
        const int gi = iz * 9 + j;          // 0..80, wave-uniform
        if (gi == 40) continue;             // skip (0,0) displacement
        const int ch = gi - (gi > 40 ? 1 : 0);
        float4 v;
        v.x = acc[j][0] * scale;
        v.y = acc[j][1] * scale;
        v.z = acc[j][2] * scale;
        v.w = acc[j][3] * scale;
        *(float4*)(outb + (size_t)ch * HW_) = v;
    }
}

extern "C" void kernel_launch(void* const* d_in, const int* in_sizes, int n_in,
                              void* d_out, int out_size, void* d_ws, size_t ws_size,
                              hipStream_t stream) {
    const float* x1 = (const float*)d_in[0];
    const float* x2 = (const float*)d_in[1];
    float* out = (float*)d_out;

    dim3 block(8, 8, 9);                       // 576 threads = 9 waves
    dim3 grid(768, 1, 1);                      // 6*16*8, linearized for swizzle
    corr_kernel<<<grid, block, 0, stream>>>(x1, x2, out);
}